// Round 11
// baseline (188.527 us; speedup 1.0000x reference)
//
#include <hip/hip_runtime.h>

#define LAMC    10000.0f
#define INV_LAM 1e-4f
#define EPSC    1e-12f
#define TOLC    1e-6f
#define BLK     256
#define WPB     (BLK / 64)           // waves per block
#define PPT     2                    // pairs per thread
#define CPB     4                    // chunks per block (pipeline depth)
#define PPC     (BLK * PPT)          // pairs per chunk = 512

__device__ __forceinline__ float frcp(float x)  { return __builtin_amdgcn_rcpf(x); }
__device__ __forceinline__ float frsq(float x)  { return __builtin_amdgcn_rsqf(x); }
__device__ __forceinline__ float fsqrt_(float x){ return __builtin_amdgcn_sqrtf(x); }

// sign(phi(t)) without sqrt/div: phi = L - R*sqrt(q), q >= EPS > 0
__device__ __forceinline__ bool phi_pos(float t, float A, float p, float N, float b) {
    float q  = fmaxf(fmaf(t, fmaf(t, A, -2.0f * p), N), EPSC);
    float L  = fmaf(-t, A, p);        // p - t*A   (U_MAX = 1)
    float R  = fmaf(t, INV_LAM, b);   // b + t/LAM
    float L2 = L * L;
    float Rq = (R * R) * q;
    return (R < 0.0f) ? ((L >= 0.0f) || (L2 < Rq))
                      : ((L >  0.0f) && (L2 > Rq));
}

// 2 independent heavy rows, interleaved chains (R7-verified algorithm):
//  bracket rows: 8 geometric bisections + 5 safeguarded clamped Newtons;
//  collapse rows (phi(0)<=0): 3 unclamped Newtons from 0, frozen after.
__device__ __forceinline__ void heavy_solve2(const float ux[2], const float uy[2],
                                             const float ax[2], const float ay[2],
                                             const float bb[2], float2 res[2]) {
    float A[2], p[2], N[2], t3[2], lo[2], hi[2];
    bool  br[2];
    #pragma unroll
    for (int r = 0; r < 2; ++r) {
        A[r] = fmaf(ax[r], ax[r], ay[r] * ay[r]);
        p[r] = fmaf(ax[r], ux[r], ay[r] * uy[r]);
        N[r] = fmaf(ux[r], ux[r], uy[r] * uy[r]);
        br[r] = phi_pos(0.0f, A[r], p[r], N[r], bb[r]);
        float tA = p[r] * frcp(fmaxf(A[r], 1e-30f));
        bool hiTA = (p[r] > 0.0f) && (fmaf(tA, INV_LAM, bb[r]) >= 0.0f);
        bool loTA = (p[r] > 0.0f) && !hiTA;
        float l = loTA ? tA : 0.0f;
        float h = hiTA ? tA : -LAMC * bb[r];
        lo[r] = br[r] ? l : 0.0f;
        hi[r] = br[r] ? h : 0.0f;
        t3[r] = 0.0f;
    }
    #pragma unroll 1
    for (int k = 0; k < 8; ++k) {            // geometric bisection, 2-way ILP
        #pragma unroll
        for (int r = 0; r < 2; ++r) {
            float fl  = fmaxf(lo[r], 1e-6f * hi[r]);
            float mid = fsqrt_(fl * hi[r]);
            bool pos  = phi_pos(mid, A[r], p[r], N[r], bb[r]);
            lo[r] = pos ? mid : lo[r];
            hi[r] = pos ? hi[r] : mid;
        }
    }
    #pragma unroll
    for (int r = 0; r < 2; ++r) t3[r] = br[r] ? 0.5f * (lo[r] + hi[r]) : 0.0f;
    #pragma unroll 1
    for (int it = 0; it < 5; ++it) {         // Newton, 2-way ILP
        #pragma unroll
        for (int r = 0; r < 2; ++r) {
            float q   = fmaxf(fmaf(t3[r], fmaf(t3[r], A[r], -2.0f * p[r]), N[r]), EPSC);
            float nrm = fsqrt_(q);
            float R   = fmaf(t3[r], INV_LAM, bb[r]);
            float f   = fmaf(-t3[r], A[r], p[r]) - R * nrm;
            float df  = -A[r] - nrm * INV_LAM - R * fmaf(t3[r], A[r], -p[r]) * frcp(nrm);
            df = (fabsf(df) > 1e-8f) ? df : -1e-8f;
            bool fp = f > 0.0f;              // phi(t3)>0 -> root above t3
            lo[r] = (br[r] && fp)  ? t3[r] : lo[r];
            hi[r] = (br[r] && !fp) ? t3[r] : hi[r];
            float tn   = t3[r] - f * frcp(df);
            float tb   = fminf(fmaxf(tn, lo[r]), hi[r]);
            float tupd = br[r] ? tb : tn;    // collapse rows: unclamped
            t3[r] = (!br[r] && it >= 3) ? t3[r] : tupd;  // freeze collapse after 3
        }
    }
    #pragma unroll
    for (int r = 0; r < 2; ++r) {
        float q3  = fmaxf(fmaf(t3[r], fmaf(t3[r], A[r], -2.0f * p[r]), N[r]), EPSC);
        float k3  = fmaxf(fsqrt_(q3), 1.0f);
        float inv = frcp(k3);
        res[r] = make_float2(fmaf(-t3[r], ax[r], ux[r]) * inv,
                             fmaf(-t3[r], ay[r], uy[r]) * inv);
    }
}

// branchless easy path; a,b precomputed. returns true if heavy (branch 3).
__device__ __forceinline__ bool easy_row(float ux, float uy,
                                         float ax, float ay, float b,
                                         float& ox, float& oy) {
    float A  = fmaf(ax, ax, ay * ay);
    float p  = fmaf(ax, ux, ay * uy);
    float N  = fmaf(ux, ux, uy * uy);
    float s1 = fminf(1.0f, frsq(fmaxf(N, EPSC)));   // min(1, 1/|u|)
    float u1x = ux * s1, u1y = uy * s1;
    bool feas1 = fmaf(ax, u1x, ay * u1y) <= b + TOLC;
    float t2  = LAMC * (p - b) * frcp(fmaf(LAMC, A, 1.0f));
    float u2x = fmaf(-t2, ax, ux), u2y = fmaf(-t2, ay, uy);
    bool ok2 = (t2 >= -TOLC) && (fmaf(u2x, u2x, u2y * u2y) <= 1.0f + TOLC);
    ox = feas1 ? u1x : u2x;
    oy = feas1 ? u1y : u2y;
    return !feas1 && !ok2;
}

struct ChunkRegs { float4 u[2]; float4 o[2][3]; };

__device__ __forceinline__ void load_chunk(const float4* __restrict__ u4,
                                           const float4* __restrict__ obs4,
                                           int pairbase, int tid, int npair,
                                           ChunkRegs& P) {
    float4 z = make_float4(0.f, 0.f, 0.f, 0.f);
    int  i0 = pairbase + tid,  i1 = pairbase + BLK + tid;
    bool v0 = i0 < npair,      v1 = i1 < npair;
    P.u[0]    = v0 ? u4[i0] : z;
    P.u[1]    = v1 ? u4[i1] : z;
    P.o[0][0] = v0 ? obs4[3 * (size_t)i0 + 0] : z;
    P.o[0][1] = v0 ? obs4[3 * (size_t)i0 + 1] : z;
    P.o[0][2] = v0 ? obs4[3 * (size_t)i0 + 2] : z;
    P.o[1][0] = v1 ? obs4[3 * (size_t)i1 + 0] : z;
    P.o[1][1] = v1 ? obs4[3 * (size_t)i1 + 1] : z;
    P.o[1][2] = v1 ? obs4[3 * (size_t)i1 + 2] : z;
}

__global__ __launch_bounds__(BLK) void cbf_kernel(const float4* __restrict__ u4,
                                                  const float4* __restrict__ obs4,
                                                  float4* __restrict__ out4,
                                                  int npair) {
    __shared__ float4 sdat[WPB][256];   // per-wave compacted heavy inputs
    __shared__ float  sbv [WPB][256];   // per-wave compacted heavy b
    // heavy results are written in place over sdat slots (float2 into float4.xy)

    int tid  = threadIdx.x;
    int wave = tid >> 6;
    int lane = tid & 63;
    unsigned long long ltmask = (1ull << lane) - 1ull;

    int chunk = blockIdx.x;             // grid-stride over chunks
    int cstep = gridDim.x;

    ChunkRegs P;
    load_chunk(u4, obs4, chunk * PPC, tid, npair, P);   // prologue prefetch

    #pragma unroll 1
    for (int c = 0; c < CPB; ++c) {
        int pairbase = chunk * PPC;
        int  i0 = pairbase + tid,  i1 = pairbase + BLK + tid;
        bool v0 = i0 < npair,      v1 = i1 < npair;

        // consume prefetched regs (compiler waits on these loads here),
        // then immediately issue next chunk's loads -> in flight during compute
        float4 ua = P.u[0], ub = P.u[1];
        float4 oa0 = P.o[0][0], oa1 = P.o[0][1], oa2 = P.o[0][2];
        float4 ob0 = P.o[1][0], ob1 = P.o[1][1], ob2 = P.o[1][2];
        chunk += cstep;
        if (c + 1 < CPB)
            load_chunk(u4, obs4, chunk * PPC, tid, npair, P);

        float4 z = make_float4(0.f, 0.f, 0.f, 0.f);
        float4 r0 = z, r1 = z;
        bool hv[4];
        float sx[4], sy[4], sax[4], say[4], sb[4];
        {
            float ax0 = -2.0f * oa0.z, ay0 = -2.0f * oa0.w;
            float b0  = fmaf(2.0f, fmaf(oa0.z, oa0.z, oa0.w * oa0.w) - 1.0f,
                             -2.0f * fmaf(oa0.z, oa1.x, oa0.w * oa1.y));
            float ax1 = -2.0f * oa2.x, ay1 = -2.0f * oa2.y;
            float b1  = fmaf(2.0f, fmaf(oa2.x, oa2.x, oa2.y * oa2.y) - 1.0f,
                             -2.0f * fmaf(oa2.x, oa2.z, oa2.y * oa2.w));
            hv[0] = v0 && easy_row(ua.x, ua.y, ax0, ay0, b0, r0.x, r0.y);
            hv[1] = v0 && easy_row(ua.z, ua.w, ax1, ay1, b1, r0.z, r0.w);
            sx[0] = ua.x; sy[0] = ua.y; sax[0] = ax0; say[0] = ay0; sb[0] = b0;
            sx[1] = ua.z; sy[1] = ua.w; sax[1] = ax1; say[1] = ay1; sb[1] = b1;
        }
        {
            float ax0 = -2.0f * ob0.z, ay0 = -2.0f * ob0.w;
            float b0  = fmaf(2.0f, fmaf(ob0.z, ob0.z, ob0.w * ob0.w) - 1.0f,
                             -2.0f * fmaf(ob0.z, ob1.x, ob0.w * ob1.y));
            float ax1 = -2.0f * ob2.x, ay1 = -2.0f * ob2.y;
            float b1  = fmaf(2.0f, fmaf(ob2.x, ob2.x, ob2.y * ob2.y) - 1.0f,
                             -2.0f * fmaf(ob2.x, ob2.z, ob2.y * ob2.w));
            hv[2] = v1 && easy_row(ub.x, ub.y, ax0, ay0, b0, r1.x, r1.y);
            hv[3] = v1 && easy_row(ub.z, ub.w, ax1, ay1, b1, r1.z, r1.w);
            sx[2] = ub.x; sy[2] = ub.y; sax[2] = ax0; say[2] = ay0; sb[2] = b0;
            sx[3] = ub.z; sy[3] = ub.w; sax[3] = ax1; say[3] = ay1; sb[3] = b1;
        }

        // wave-local ballot compaction into per-wave staging
        int tot = 0;
        int slot[4];
        #pragma unroll
        for (int m = 0; m < 4; ++m) {
            unsigned long long mm = __ballot(hv[m]);
            slot[m] = tot + __popcll(mm & ltmask);
            if (hv[m]) {
                sdat[wave][slot[m]] = make_float4(sx[m], sy[m], sax[m], say[m]);
                sbv [wave][slot[m]] = sb[m];
            }
            tot += __popcll(mm);
        }
        __threadfence_block();   // wave lockstep + lgkmcnt drain orders LDS w->r

        // heavy batches: 2 rows/lane, results written in place
        #pragma unroll 1
        for (int base = 0; base < tot; base += 128) {
            float hux[2], huy[2], hax[2], hay[2], hbb[2];
            float2 hres[2];
            int jj[2];
            #pragma unroll
            for (int q = 0; q < 2; ++q) {
                int j  = base + q * 64 + lane;
                jj[q]  = j;
                int js = (j < tot) ? j : (tot - 1);  // clamp: dup work, no store
                float4 d = sdat[wave][js];
                hux[q] = d.x;  huy[q] = d.y;  hax[q] = d.z;  hay[q] = d.w;
                hbb[q] = sbv[wave][js];
            }
            heavy_solve2(hux, huy, hax, hay, hbb, hres);
            #pragma unroll
            for (int q = 0; q < 2; ++q)
                if (jj[q] < tot) *(float2*)&sdat[wave][jj[q]] = hres[q];
        }
        __threadfence_block();

        if (hv[0]) { float2 s = *(const float2*)&sdat[wave][slot[0]]; r0.x = s.x; r0.y = s.y; }
        if (hv[1]) { float2 s = *(const float2*)&sdat[wave][slot[1]]; r0.z = s.x; r0.w = s.y; }
        if (hv[2]) { float2 s = *(const float2*)&sdat[wave][slot[2]]; r1.x = s.x; r1.y = s.y; }
        if (hv[3]) { float2 s = *(const float2*)&sdat[wave][slot[3]]; r1.z = s.x; r1.w = s.y; }

        // per-wave in-order LDS: the reads above complete before next
        // iteration's compaction writes; fence keeps compiler honest
        asm volatile("s_waitcnt lgkmcnt(0)" ::: "memory");

        if (v0) out4[i0] = r0;                 // contiguous, coalesced
        if (v1) out4[i1] = r1;
    }
}

extern "C" void kernel_launch(void* const* d_in, const int* in_sizes, int n_in,
                              void* d_out, int out_size, void* d_ws, size_t ws_size,
                              hipStream_t stream) {
    const float* u_nom = (const float*)d_in[0];
    const float* obs   = (const float*)d_in[1];
    float* out = (float*)d_out;
    int rows   = in_sizes[0] / 2;                    // B
    int npair  = rows / 2;                           // 2 rows per thread-slot
    int nchunk = (npair + PPC - 1) / PPC;            // 4096 at B=4M
    int blocks = (nchunk + CPB - 1) / CPB;           // 1024
    cbf_kernel<<<blocks, BLK, 0, stream>>>((const float4*)u_nom,
                                           (const float4*)obs,
                                           (float4*)out, npair);
}

// Round 12
// 188.439 us; speedup vs baseline: 1.0005x; 1.0005x over previous
//
#include <hip/hip_runtime.h>

#define LAMC    10000.0f
#define INV_LAM 1e-4f
#define EPSC    1e-12f
#define TOLC    1e-6f
#define BLK     256
#define WPB     (BLK / 64)           // waves per block
#define PPT     2                    // pairs per thread
#define CPB     2                    // chunks per block (pipeline depth)
#define PPC     (BLK * PPT)          // pairs per chunk = 512

__device__ __forceinline__ float frcp(float x)  { return __builtin_amdgcn_rcpf(x); }
__device__ __forceinline__ float frsq(float x)  { return __builtin_amdgcn_rsqf(x); }
__device__ __forceinline__ float fsqrt_(float x){ return __builtin_amdgcn_sqrtf(x); }

// LDS-only ordering fence: waits DS queue, does NOT drain global loads/stores
// (__threadfence_block would s_waitcnt vmcnt(0) and kill the load pipeline)
#define LDS_FENCE() asm volatile("s_waitcnt lgkmcnt(0)" ::: "memory")

// sign(phi(t)) without sqrt/div: phi = L - R*sqrt(q), q >= EPS > 0
__device__ __forceinline__ bool phi_pos(float t, float A, float p, float N, float b) {
    float q  = fmaxf(fmaf(t, fmaf(t, A, -2.0f * p), N), EPSC);
    float L  = fmaf(-t, A, p);        // p - t*A   (U_MAX = 1)
    float R  = fmaf(t, INV_LAM, b);   // b + t/LAM
    float L2 = L * L;
    float Rq = (R * R) * q;
    return (R < 0.0f) ? ((L >= 0.0f) || (L2 < Rq))
                      : ((L >  0.0f) && (L2 > Rq));
}

// 2 independent heavy rows, interleaved chains (R7-verified algorithm):
//  bracket rows: 8 geometric bisections + 5 safeguarded clamped Newtons;
//  collapse rows (phi(0)<=0): 3 unclamped Newtons from 0, frozen after.
__device__ __forceinline__ void heavy_solve2(const float ux[2], const float uy[2],
                                             const float ax[2], const float ay[2],
                                             const float bb[2], float2 res[2]) {
    float A[2], p[2], N[2], t3[2], lo[2], hi[2];
    bool  br[2];
    #pragma unroll
    for (int r = 0; r < 2; ++r) {
        A[r] = fmaf(ax[r], ax[r], ay[r] * ay[r]);
        p[r] = fmaf(ax[r], ux[r], ay[r] * uy[r]);
        N[r] = fmaf(ux[r], ux[r], uy[r] * uy[r]);
        br[r] = phi_pos(0.0f, A[r], p[r], N[r], bb[r]);
        float tA = p[r] * frcp(fmaxf(A[r], 1e-30f));
        bool hiTA = (p[r] > 0.0f) && (fmaf(tA, INV_LAM, bb[r]) >= 0.0f);
        bool loTA = (p[r] > 0.0f) && !hiTA;
        float l = loTA ? tA : 0.0f;
        float h = hiTA ? tA : -LAMC * bb[r];
        lo[r] = br[r] ? l : 0.0f;
        hi[r] = br[r] ? h : 0.0f;
        t3[r] = 0.0f;
    }
    #pragma unroll 1
    for (int k = 0; k < 8; ++k) {            // geometric bisection, 2-way ILP
        #pragma unroll
        for (int r = 0; r < 2; ++r) {
            float fl  = fmaxf(lo[r], 1e-6f * hi[r]);
            float mid = fsqrt_(fl * hi[r]);
            bool pos  = phi_pos(mid, A[r], p[r], N[r], bb[r]);
            lo[r] = pos ? mid : lo[r];
            hi[r] = pos ? hi[r] : mid;
        }
    }
    #pragma unroll
    for (int r = 0; r < 2; ++r) t3[r] = br[r] ? 0.5f * (lo[r] + hi[r]) : 0.0f;
    #pragma unroll 1
    for (int it = 0; it < 5; ++it) {         // Newton, 2-way ILP
        #pragma unroll
        for (int r = 0; r < 2; ++r) {
            float q   = fmaxf(fmaf(t3[r], fmaf(t3[r], A[r], -2.0f * p[r]), N[r]), EPSC);
            float nrm = fsqrt_(q);
            float R   = fmaf(t3[r], INV_LAM, bb[r]);
            float f   = fmaf(-t3[r], A[r], p[r]) - R * nrm;
            float df  = -A[r] - nrm * INV_LAM - R * fmaf(t3[r], A[r], -p[r]) * frcp(nrm);
            df = (fabsf(df) > 1e-8f) ? df : -1e-8f;
            bool fp = f > 0.0f;              // phi(t3)>0 -> root above t3
            lo[r] = (br[r] && fp)  ? t3[r] : lo[r];
            hi[r] = (br[r] && !fp) ? t3[r] : hi[r];
            float tn   = t3[r] - f * frcp(df);
            float tb   = fminf(fmaxf(tn, lo[r]), hi[r]);
            float tupd = br[r] ? tb : tn;    // collapse rows: unclamped
            t3[r] = (!br[r] && it >= 3) ? t3[r] : tupd;  // freeze collapse after 3
        }
    }
    #pragma unroll
    for (int r = 0; r < 2; ++r) {
        float q3  = fmaxf(fmaf(t3[r], fmaf(t3[r], A[r], -2.0f * p[r]), N[r]), EPSC);
        float k3  = fmaxf(fsqrt_(q3), 1.0f);
        float inv = frcp(k3);
        res[r] = make_float2(fmaf(-t3[r], ax[r], ux[r]) * inv,
                             fmaf(-t3[r], ay[r], uy[r]) * inv);
    }
}

// branchless easy path; a,b precomputed. returns true if heavy (branch 3).
__device__ __forceinline__ bool easy_row(float ux, float uy,
                                         float ax, float ay, float b,
                                         float& ox, float& oy) {
    float A  = fmaf(ax, ax, ay * ay);
    float p  = fmaf(ax, ux, ay * uy);
    float N  = fmaf(ux, ux, uy * uy);
    float s1 = fminf(1.0f, frsq(fmaxf(N, EPSC)));   // min(1, 1/|u|)
    float u1x = ux * s1, u1y = uy * s1;
    bool feas1 = fmaf(ax, u1x, ay * u1y) <= b + TOLC;
    float t2  = LAMC * (p - b) * frcp(fmaf(LAMC, A, 1.0f));
    float u2x = fmaf(-t2, ax, ux), u2y = fmaf(-t2, ay, uy);
    bool ok2 = (t2 >= -TOLC) && (fmaf(u2x, u2x, u2y * u2y) <= 1.0f + TOLC);
    ox = feas1 ? u1x : u2x;
    oy = feas1 ? u1y : u2y;
    return !feas1 && !ok2;
}

struct ChunkRegs { float4 u[2]; float4 o[2][3]; };

__device__ __forceinline__ void load_chunk(const float4* __restrict__ u4,
                                           const float4* __restrict__ obs4,
                                           int pairbase, int tid, int npair,
                                           ChunkRegs& P) {
    float4 z = make_float4(0.f, 0.f, 0.f, 0.f);
    int  i0 = pairbase + tid,  i1 = pairbase + BLK + tid;
    bool v0 = i0 < npair,      v1 = i1 < npair;
    P.u[0]    = v0 ? u4[i0] : z;
    P.u[1]    = v1 ? u4[i1] : z;
    P.o[0][0] = v0 ? obs4[3 * (size_t)i0 + 0] : z;
    P.o[0][1] = v0 ? obs4[3 * (size_t)i0 + 1] : z;
    P.o[0][2] = v0 ? obs4[3 * (size_t)i0 + 2] : z;
    P.o[1][0] = v1 ? obs4[3 * (size_t)i1 + 0] : z;
    P.o[1][1] = v1 ? obs4[3 * (size_t)i1 + 1] : z;
    P.o[1][2] = v1 ? obs4[3 * (size_t)i1 + 2] : z;
}

__global__ __launch_bounds__(BLK) void cbf_kernel(const float4* __restrict__ u4,
                                                  const float4* __restrict__ obs4,
                                                  float4* __restrict__ out4,
                                                  int npair) {
    __shared__ float4 sdat[WPB][256];   // per-wave compacted heavy inputs
    __shared__ float  sbv [WPB][256];   // per-wave compacted heavy b
    // heavy results are written in place over sdat slots (float2 into float4.xy)

    int tid  = threadIdx.x;
    int wave = tid >> 6;
    int lane = tid & 63;
    unsigned long long ltmask = (1ull << lane) - 1ull;

    int chunk = blockIdx.x;             // grid-stride over chunks
    int cstep = gridDim.x;

    ChunkRegs P;
    load_chunk(u4, obs4, chunk * PPC, tid, npair, P);   // prologue prefetch

    #pragma unroll 1
    for (int c = 0; c < CPB; ++c) {
        int pairbase = chunk * PPC;
        int  i0 = pairbase + tid,  i1 = pairbase + BLK + tid;
        bool v0 = i0 < npair,      v1 = i1 < npair;

        // consume prefetched regs (compiler waits on these loads here),
        // then immediately issue next chunk's loads -> in flight during compute
        float4 ua = P.u[0], ub = P.u[1];
        float4 oa0 = P.o[0][0], oa1 = P.o[0][1], oa2 = P.o[0][2];
        float4 ob0 = P.o[1][0], ob1 = P.o[1][1], ob2 = P.o[1][2];
        chunk += cstep;
        if (c + 1 < CPB)
            load_chunk(u4, obs4, chunk * PPC, tid, npair, P);

        float4 z = make_float4(0.f, 0.f, 0.f, 0.f);
        float4 r0 = z, r1 = z;
        bool hv[4];
        float sx[4], sy[4], sax[4], say[4], sb[4];
        {
            float ax0 = -2.0f * oa0.z, ay0 = -2.0f * oa0.w;
            float b0  = fmaf(2.0f, fmaf(oa0.z, oa0.z, oa0.w * oa0.w) - 1.0f,
                             -2.0f * fmaf(oa0.z, oa1.x, oa0.w * oa1.y));
            float ax1 = -2.0f * oa2.x, ay1 = -2.0f * oa2.y;
            float b1  = fmaf(2.0f, fmaf(oa2.x, oa2.x, oa2.y * oa2.y) - 1.0f,
                             -2.0f * fmaf(oa2.x, oa2.z, oa2.y * oa2.w));
            hv[0] = v0 && easy_row(ua.x, ua.y, ax0, ay0, b0, r0.x, r0.y);
            hv[1] = v0 && easy_row(ua.z, ua.w, ax1, ay1, b1, r0.z, r0.w);
            sx[0] = ua.x; sy[0] = ua.y; sax[0] = ax0; say[0] = ay0; sb[0] = b0;
            sx[1] = ua.z; sy[1] = ua.w; sax[1] = ax1; say[1] = ay1; sb[1] = b1;
        }
        {
            float ax0 = -2.0f * ob0.z, ay0 = -2.0f * ob0.w;
            float b0  = fmaf(2.0f, fmaf(ob0.z, ob0.z, ob0.w * ob0.w) - 1.0f,
                             -2.0f * fmaf(ob0.z, ob1.x, ob0.w * ob1.y));
            float ax1 = -2.0f * ob2.x, ay1 = -2.0f * ob2.y;
            float b1  = fmaf(2.0f, fmaf(ob2.x, ob2.x, ob2.y * ob2.y) - 1.0f,
                             -2.0f * fmaf(ob2.x, ob2.z, ob2.y * ob2.w));
            hv[2] = v1 && easy_row(ub.x, ub.y, ax0, ay0, b0, r1.x, r1.y);
            hv[3] = v1 && easy_row(ub.z, ub.w, ax1, ay1, b1, r1.z, r1.w);
            sx[2] = ub.x; sy[2] = ub.y; sax[2] = ax0; say[2] = ay0; sb[2] = b0;
            sx[3] = ub.z; sy[3] = ub.w; sax[3] = ax1; say[3] = ay1; sb[3] = b1;
        }

        // wave-local ballot compaction into per-wave staging
        int tot = 0;
        int slot[4];
        #pragma unroll
        for (int m = 0; m < 4; ++m) {
            unsigned long long mm = __ballot(hv[m]);
            slot[m] = tot + __popcll(mm & ltmask);
            if (hv[m]) {
                sdat[wave][slot[m]] = make_float4(sx[m], sy[m], sax[m], say[m]);
                sbv [wave][slot[m]] = sb[m];
            }
            tot += __popcll(mm);
        }
        LDS_FENCE();   // DS-only drain: wave-local LDS w->r ordering

        // heavy batches: 2 rows/lane, results written in place
        #pragma unroll 1
        for (int base = 0; base < tot; base += 128) {
            float hux[2], huy[2], hax[2], hay[2], hbb[2];
            float2 hres[2];
            int jj[2];
            #pragma unroll
            for (int q = 0; q < 2; ++q) {
                int j  = base + q * 64 + lane;
                jj[q]  = j;
                int js = (j < tot) ? j : (tot - 1);  // clamp: dup work, no store
                float4 d = sdat[wave][js];
                hux[q] = d.x;  huy[q] = d.y;  hax[q] = d.z;  hay[q] = d.w;
                hbb[q] = sbv[wave][js];
            }
            heavy_solve2(hux, huy, hax, hay, hbb, hres);
            #pragma unroll
            for (int q = 0; q < 2; ++q)
                if (jj[q] < tot) *(float2*)&sdat[wave][jj[q]] = hres[q];
        }
        LDS_FENCE();   // DS-only drain: results visible to readback

        if (hv[0]) { float2 s = *(const float2*)&sdat[wave][slot[0]]; r0.x = s.x; r0.y = s.y; }
        if (hv[1]) { float2 s = *(const float2*)&sdat[wave][slot[1]]; r0.z = s.x; r0.w = s.y; }
        if (hv[2]) { float2 s = *(const float2*)&sdat[wave][slot[2]]; r1.x = s.x; r1.y = s.y; }
        if (hv[3]) { float2 s = *(const float2*)&sdat[wave][slot[3]]; r1.z = s.x; r1.w = s.y; }

        LDS_FENCE();   // readback lands before next iteration's compaction writes

        if (v0) out4[i0] = r0;                 // contiguous, coalesced
        if (v1) out4[i1] = r1;
    }
}

extern "C" void kernel_launch(void* const* d_in, const int* in_sizes, int n_in,
                              void* d_out, int out_size, void* d_ws, size_t ws_size,
                              hipStream_t stream) {
    const float* u_nom = (const float*)d_in[0];
    const float* obs   = (const float*)d_in[1];
    float* out = (float*)d_out;
    int rows   = in_sizes[0] / 2;                    // B
    int npair  = rows / 2;                           // 2 rows per thread-slot
    int nchunk = (npair + PPC - 1) / PPC;            // 4096 at B=4M
    int blocks = (nchunk + CPB - 1) / CPB;           // 2048 -> 8 blocks/CU
    cbf_kernel<<<blocks, BLK, 0, stream>>>((const float4*)u_nom,
                                           (const float4*)obs,
                                           (float4*)out, npair);
}

// Round 13
// 179.135 us; speedup vs baseline: 1.0524x; 1.0519x over previous
//
#include <hip/hip_runtime.h>

#define LAMC    10000.0f
#define INV_LAM 1e-4f
#define EPSC    1e-12f
#define TOLC    1e-6f
#define BLK     256

__device__ __forceinline__ float frcp(float x)  { return __builtin_amdgcn_rcpf(x); }
__device__ __forceinline__ float frsq(float x)  { return __builtin_amdgcn_rsqf(x); }
__device__ __forceinline__ float fsqrt_(float x){ return __builtin_amdgcn_sqrtf(x); }

// sign(phi(t)) without sqrt/div: phi = L - R*sqrt(q), q >= EPS > 0
__device__ __forceinline__ bool phi_pos(float t, float A, float p, float N, float b) {
    float q  = fmaxf(fmaf(t, fmaf(t, A, -2.0f * p), N), EPSC);
    float L  = fmaf(-t, A, p);        // p - t*A   (U_MAX = 1)
    float R  = fmaf(t, INV_LAM, b);   // b + t/LAM
    float L2 = L * L;
    float Rq = (R * R) * q;
    return (R < 0.0f) ? ((L >= 0.0f) || (L2 < Rq))
                      : ((L >  0.0f) && (L2 > Rq));
}

// 2 independent heavy rows, interleaved chains (R7-verified algorithm, with
// Newton count 5->3: geometric bisection leaves a <=2.7%-wide bracket; each
// safeguarded step at worst halves it (midpoint fallback) -> <=0.34% after 3,
// far inside the bf16-0.02 tolerance (needs ~1.5% in t). Collapse rows
// (phi(0)<=0) need exactly 3 unclamped Newtons from 0 (reference), so the
// loop unifies at 3 with no freeze logic.
__device__ __forceinline__ void heavy_solve2(const float ux[2], const float uy[2],
                                             const float ax[2], const float ay[2],
                                             const float bb[2], float2 res[2]) {
    float A[2], p[2], N[2], t3[2], lo[2], hi[2];
    bool  br[2];
    #pragma unroll
    for (int r = 0; r < 2; ++r) {
        A[r] = fmaf(ax[r], ax[r], ay[r] * ay[r]);
        p[r] = fmaf(ax[r], ux[r], ay[r] * uy[r]);
        N[r] = fmaf(ux[r], ux[r], uy[r] * uy[r]);
        br[r] = phi_pos(0.0f, A[r], p[r], N[r], bb[r]);
        float tA = p[r] * frcp(fmaxf(A[r], 1e-30f));
        bool hiTA = (p[r] > 0.0f) && (fmaf(tA, INV_LAM, bb[r]) >= 0.0f);
        bool loTA = (p[r] > 0.0f) && !hiTA;
        float l = loTA ? tA : 0.0f;
        float h = hiTA ? tA : -LAMC * bb[r];
        lo[r] = br[r] ? l : 0.0f;
        hi[r] = br[r] ? h : 0.0f;
        t3[r] = 0.0f;
    }
    #pragma unroll 1
    for (int k = 0; k < 8; ++k) {            // geometric bisection, 2-way ILP
        #pragma unroll
        for (int r = 0; r < 2; ++r) {
            float fl  = fmaxf(lo[r], 1e-6f * hi[r]);
            float mid = fsqrt_(fl * hi[r]);
            bool pos  = phi_pos(mid, A[r], p[r], N[r], bb[r]);
            lo[r] = pos ? mid : lo[r];
            hi[r] = pos ? hi[r] : mid;
        }
    }
    #pragma unroll
    for (int r = 0; r < 2; ++r) t3[r] = br[r] ? 0.5f * (lo[r] + hi[r]) : 0.0f;
    #pragma unroll 1
    for (int it = 0; it < 3; ++it) {         // Newton, 2-way ILP
        #pragma unroll
        for (int r = 0; r < 2; ++r) {
            float q   = fmaxf(fmaf(t3[r], fmaf(t3[r], A[r], -2.0f * p[r]), N[r]), EPSC);
            float nrm = fsqrt_(q);
            float R   = fmaf(t3[r], INV_LAM, bb[r]);
            float f   = fmaf(-t3[r], A[r], p[r]) - R * nrm;
            float df  = -A[r] - nrm * INV_LAM - R * fmaf(t3[r], A[r], -p[r]) * frcp(nrm);
            df = (fabsf(df) > 1e-8f) ? df : -1e-8f;
            bool fp = f > 0.0f;              // phi(t3)>0 -> root above t3
            lo[r] = (br[r] && fp)  ? t3[r] : lo[r];
            hi[r] = (br[r] && !fp) ? t3[r] : hi[r];
            float tn = t3[r] - f * frcp(df);
            float tb = fminf(fmaxf(tn, lo[r]), hi[r]);
            t3[r] = br[r] ? tb : tn;         // collapse rows: unclamped
        }
    }
    #pragma unroll
    for (int r = 0; r < 2; ++r) {
        float q3  = fmaxf(fmaf(t3[r], fmaf(t3[r], A[r], -2.0f * p[r]), N[r]), EPSC);
        float k3  = fmaxf(fsqrt_(q3), 1.0f);
        float inv = frcp(k3);
        res[r] = make_float2(fmaf(-t3[r], ax[r], ux[r]) * inv,
                             fmaf(-t3[r], ay[r], uy[r]) * inv);
    }
}

// branchless easy path; a,b precomputed. returns true if heavy (branch 3).
__device__ __forceinline__ bool easy_row(float ux, float uy,
                                         float ax, float ay, float b,
                                         float& ox, float& oy) {
    float A  = fmaf(ax, ax, ay * ay);
    float p  = fmaf(ax, ux, ay * uy);
    float N  = fmaf(ux, ux, uy * uy);
    float s1 = fminf(1.0f, frsq(fmaxf(N, EPSC)));   // min(1, 1/|u|)
    float u1x = ux * s1, u1y = uy * s1;
    bool feas1 = fmaf(ax, u1x, ay * u1y) <= b + TOLC;
    float t2  = LAMC * (p - b) * frcp(fmaf(LAMC, A, 1.0f));
    float u2x = fmaf(-t2, ax, ux), u2y = fmaf(-t2, ay, uy);
    bool ok2 = (t2 >= -TOLC) && (fmaf(u2x, u2x, u2y * u2y) <= 1.0f + TOLC);
    ox = feas1 ? u1x : u2x;
    oy = feas1 ? u1y : u2y;
    return !feas1 && !ok2;
}

// No LDS, no ballots, no fences: since the heavy solver processes 2 rows per
// lane anyway, wave-level compaction no longer reduces solver executions
// (1x heavy_solve2 per thread either way at ~45% heavy fraction) — it only
// added LDS round-trips and full lgkmcnt drains. Each thread solves its own
// two rows, masked; the solver is skipped only if the whole wave is easy.
__global__ __launch_bounds__(BLK) void cbf_kernel(const float4* __restrict__ u4,
                                                  const float4* __restrict__ obs4,
                                                  float4* __restrict__ out4,
                                                  int npair) {
    int i = blockIdx.x * BLK + threadIdx.x;
    bool valid = i < npair;
    float4 z = make_float4(0.f, 0.f, 0.f, 0.f);
    float4 u  = valid ? u4[i]           : z;
    float4 o0 = valid ? obs4[3 * i + 0] : z;
    float4 o1 = valid ? obs4[3 * i + 1] : z;
    float4 o2 = valid ? obs4[3 * i + 2] : z;

    // row 2i:   p=(o0.z,o0.w)  v=(o1.x,o1.y)
    // row 2i+1: p=(o2.x,o2.y)  v=(o2.z,o2.w)
    float ax0 = -2.0f * o0.z, ay0 = -2.0f * o0.w;
    float b0  = fmaf(2.0f, fmaf(o0.z, o0.z, o0.w * o0.w) - 1.0f,
                     -2.0f * fmaf(o0.z, o1.x, o0.w * o1.y));
    float ax1 = -2.0f * o2.x, ay1 = -2.0f * o2.y;
    float b1  = fmaf(2.0f, fmaf(o2.x, o2.x, o2.y * o2.y) - 1.0f,
                     -2.0f * fmaf(o2.x, o2.z, o2.y * o2.w));

    float4 r = z;
    bool h0 = valid && easy_row(u.x, u.y, ax0, ay0, b0, r.x, r.y);
    bool h1 = valid && easy_row(u.z, u.w, ax1, ay1, b1, r.z, r.w);

    if (__builtin_amdgcn_ballot_w64(h0 || h1)) {   // skip only if whole wave easy
        float ux[2] = { u.x, u.z },  uy[2] = { u.y, u.w };
        float ax[2] = { ax0, ax1 },  ay[2] = { ay0, ay1 };
        float bb[2] = { b0, b1 };
        float2 res[2];
        heavy_solve2(ux, uy, ax, ay, bb, res);
        if (h0) { r.x = res[0].x; r.y = res[0].y; }
        if (h1) { r.z = res[1].x; r.w = res[1].y; }
    }

    if (valid) out4[i] = r;
}

extern "C" void kernel_launch(void* const* d_in, const int* in_sizes, int n_in,
                              void* d_out, int out_size, void* d_ws, size_t ws_size,
                              hipStream_t stream) {
    const float* u_nom = (const float*)d_in[0];
    const float* obs   = (const float*)d_in[1];
    float* out = (float*)d_out;
    int rows   = in_sizes[0] / 2;     // B
    int npair  = rows / 2;            // 2 rows per thread
    int blocks = (npair + BLK - 1) / BLK;
    cbf_kernel<<<blocks, BLK, 0, stream>>>((const float4*)u_nom,
                                           (const float4*)obs,
                                           (float4*)out, npair);
}

// Round 14
// 179.075 us; speedup vs baseline: 1.0528x; 1.0003x over previous
//
#include <hip/hip_runtime.h>

#define LAMC    10000.0f
#define INV_LAM 1e-4f
#define EPSC    1e-12f
#define TOLC    1e-6f
#define BLK     256

__device__ __forceinline__ float frcp(float x)  { return __builtin_amdgcn_rcpf(x); }
__device__ __forceinline__ float frsq(float x)  { return __builtin_amdgcn_rsqf(x); }
__device__ __forceinline__ float fsqrt_(float x){ return __builtin_amdgcn_sqrtf(x); }

// sign(phi(t)) without sqrt/div: phi = L - R*sqrt(q), q >= EPS > 0
__device__ __forceinline__ bool phi_pos(float t, float A, float p, float N, float b) {
    float q  = fmaxf(fmaf(t, fmaf(t, A, -2.0f * p), N), EPSC);
    float L  = fmaf(-t, A, p);        // p - t*A   (U_MAX = 1)
    float R  = fmaf(t, INV_LAM, b);   // b + t/LAM
    float L2 = L * L;
    float Rq = (R * R) * q;
    return (R < 0.0f) ? ((L >= 0.0f) || (L2 < Rq))
                      : ((L >  0.0f) && (L2 > Rq));
}

// single-row heavy solve — per-row math bit-identical to R13's passing kernel:
//  bracket rows: 8 geometric bisections + 3 safeguarded clamped Newtons;
//  collapse rows (phi(0)<=0): 3 unclamped Newtons from 0. Unified loop.
__device__ __forceinline__ float2 heavy_solve1(float ux, float uy,
                                               float ax, float ay, float b) {
    float A = fmaf(ax, ax, ay * ay);
    float p = fmaf(ax, ux, ay * uy);
    float N = fmaf(ux, ux, uy * uy);
    bool  br = phi_pos(0.0f, A, p, N, b);
    float tA = p * frcp(fmaxf(A, 1e-30f));
    bool hiTA = (p > 0.0f) && (fmaf(tA, INV_LAM, b) >= 0.0f);
    bool loTA = (p > 0.0f) && !hiTA;
    float lo = br ? (loTA ? tA : 0.0f) : 0.0f;
    float hi = br ? (hiTA ? tA : -LAMC * b) : 0.0f;

    #pragma unroll 1
    for (int k = 0; k < 8; ++k) {            // geometric bisection
        float fl  = fmaxf(lo, 1e-6f * hi);
        float mid = fsqrt_(fl * hi);
        bool pos  = phi_pos(mid, A, p, N, b);
        lo = pos ? mid : lo;
        hi = pos ? hi : mid;
    }
    float t3 = br ? 0.5f * (lo + hi) : 0.0f;

    #pragma unroll 1
    for (int it = 0; it < 3; ++it) {         // safeguarded / unclamped Newton
        float q   = fmaxf(fmaf(t3, fmaf(t3, A, -2.0f * p), N), EPSC);
        float nrm = fsqrt_(q);
        float R   = fmaf(t3, INV_LAM, b);
        float f   = fmaf(-t3, A, p) - R * nrm;
        float df  = -A - nrm * INV_LAM - R * fmaf(t3, A, -p) * frcp(nrm);
        df = (fabsf(df) > 1e-8f) ? df : -1e-8f;
        bool fp = f > 0.0f;                  // phi(t3)>0 -> root above t3
        lo = (br && fp)  ? t3 : lo;
        hi = (br && !fp) ? t3 : hi;
        float tn = t3 - f * frcp(df);
        float tb = fminf(fmaxf(tn, lo), hi);
        t3 = br ? tb : tn;                   // collapse rows: unclamped
    }
    float q3  = fmaxf(fmaf(t3, fmaf(t3, A, -2.0f * p), N), EPSC);
    float k3  = fmaxf(fsqrt_(q3), 1.0f);
    float inv = frcp(k3);
    return make_float2(fmaf(-t3, ax, ux) * inv, fmaf(-t3, ay, uy) * inv);
}

// branchless easy path; a,b precomputed. returns true if heavy (branch 3).
__device__ __forceinline__ bool easy_row(float ux, float uy,
                                         float ax, float ay, float b,
                                         float& ox, float& oy) {
    float A  = fmaf(ax, ax, ay * ay);
    float p  = fmaf(ax, ux, ay * uy);
    float N  = fmaf(ux, ux, uy * uy);
    float s1 = fminf(1.0f, frsq(fmaxf(N, EPSC)));   // min(1, 1/|u|)
    float u1x = ux * s1, u1y = uy * s1;
    bool feas1 = fmaf(ax, u1x, ay * u1y) <= b + TOLC;
    float t2  = LAMC * (p - b) * frcp(fmaf(LAMC, A, 1.0f));
    float u2x = fmaf(-t2, ax, ux), u2y = fmaf(-t2, ay, uy);
    bool ok2 = (t2 >= -TOLC) && (fmaf(u2x, u2x, u2y * u2y) <= 1.0f + TOLC);
    ox = feas1 ? u1x : u2x;
    oy = feas1 ? u1y : u2y;
    return !feas1 && !ok2;
}

// 1 ROW PER THREAD: halves the per-wave serial dependency chain (the last
// unisolated axis — all prior variants carried >=2 rows/lane). 4M threads,
// 16384 blocks; 8B/lane loads (coalescing sweet spot); request count proven
// irrelevant in R10. Solver skipped only if the entire wave is easy.
__global__ __launch_bounds__(BLK) void cbf_kernel(const float2* __restrict__ u2v,
                                                  const float*  __restrict__ obs,
                                                  float2* __restrict__ out2,
                                                  int nrows) {
    int i = blockIdx.x * BLK + threadIdx.x;
    bool valid = i < nrows;
    int j = valid ? i : 0;

    float2 u  = u2v[j];                                  // 8B, contiguous
    float2 pr = *(const float2*)(obs + 6 * (size_t)j + 2);  // 8B, stride 24B
    float2 vv = *(const float2*)(obs + 6 * (size_t)j + 4);

    float ax = -2.0f * pr.x, ay = -2.0f * pr.y;
    float b  = fmaf(2.0f, fmaf(pr.x, pr.x, pr.y * pr.y) - 1.0f,
                    -2.0f * fmaf(pr.x, vv.x, pr.y * vv.y));

    float2 r;
    bool h = easy_row(u.x, u.y, ax, ay, b, r.x, r.y) && valid;

    if (__builtin_amdgcn_ballot_w64(h))      // skip only if whole wave easy
        if (true) {                          // masked per-lane result select
            float2 s = heavy_solve1(u.x, u.y, ax, ay, b);
            if (h) r = s;
        }

    if (valid) out2[i] = r;
}

extern "C" void kernel_launch(void* const* d_in, const int* in_sizes, int n_in,
                              void* d_out, int out_size, void* d_ws, size_t ws_size,
                              hipStream_t stream) {
    const float* u_nom = (const float*)d_in[0];
    const float* obs   = (const float*)d_in[1];
    float* out = (float*)d_out;
    int nrows  = in_sizes[0] / 2;     // B rows, 1 per thread
    int blocks = (nrows + BLK - 1) / BLK;
    cbf_kernel<<<blocks, BLK, 0, stream>>>((const float2*)u_nom, obs,
                                           (float2*)out, nrows);
}